// Round 9
// baseline (2841.039 us; speedup 1.0000x reference)
//
#include <hip/hip_runtime.h>
#include <hip/hip_bf16.h>
#include <cstdint>

typedef __bf16 bf16_t;
typedef __bf16 bf16x4 __attribute__((ext_vector_type(4)));
typedef __bf16 bf16x8 __attribute__((ext_vector_type(8)));
typedef float f32x4 __attribute__((ext_vector_type(4)));

#define BATCH 4096
#define DIN   1024
#define HID   2048
#define DOUT  1000
#define NITER 50
#define LR    0.001f

#define BM 128
#define BN 128
#define BK 32
#define NBUF 4

// async global -> LDS, 16 B per lane. LDS dest is wave-uniform base + lane*16.
#define GLDS(g, l)                                                        \
    __builtin_amdgcn_global_load_lds(                                     \
        (const __attribute__((address_space(1))) void*)(g),               \
        (__attribute__((address_space(3))) void*)(l), 16, 0, 0)

#define WAITVM(N) asm volatile("s_waitcnt vmcnt(" #N ")" ::: "memory")
#define BAR()     __builtin_amdgcn_s_barrier()
#define SCHEDB()  __builtin_amdgcn_sched_barrier(0)

__device__ __forceinline__ unsigned int bf16_bits(float f) {
    bf16_t h = (bf16_t)f;
    unsigned short s;
    __builtin_memcpy(&s, &h, 2);
    return (unsigned int)s;
}
__device__ __forceinline__ float bf16_val(unsigned short s) {
    unsigned int u = (unsigned int)s << 16;
    float f;
    __builtin_memcpy(&f, &u, 4);
    return f;
}

// ---------------------------------------------------------------------------
// Persistent kernel WITHOUT cooperative launch (R8's failed silently).
// Grid = 256 blocks = 1 per CU (96 KB LDS + 512 thr force occupancy 1/CU,
// so all 256 blocks are co-resident by construction -> manual barriers safe).
// Block b = (m = b>>3, n = b&7): per iteration computes BOTH
//   U tile: D_u = e_x @ Wg  (cols n*128..)   -> u += LR*D_u; e_x' = x - sig(u)
//   Z tile: D_z = e_x @ Wc^T (cols n*128..)  -> z += LR*D_z; e_y recurrence
// with ONE shared A-stage (e_x) and two B-streams (Wg, Wc): 32 MFMA/K-pair.
// u, z, e_y live in REGISTERS across all 50 iterations.
// Cross-block dep is only e_x within an m-slice: 8-block slice barrier via
// monotonic device-scope atomic counter + __threadfence (cross-XCD safe).
// K-loop: 4 LDS buffers, 2 K-tiles per barrier pair, counted vmcnt (T4):
// 3 loads/thread/tile, steady WAITVM(6), tail 6 -> 0.
// ---------------------------------------------------------------------------
__global__ __launch_bounds__(512, 2) void pc_persist(
    bf16_t* __restrict__ exA, bf16_t* __restrict__ exB,
    const bf16_t* __restrict__ wg, const bf16_t* __restrict__ wc,
    const float* __restrict__ xin, const float* __restrict__ bias_g,
    const float* __restrict__ bias_o,
    float* __restrict__ yout, float* __restrict__ energy,
    unsigned int* __restrict__ barcnt)
{
    __shared__ __align__(16) bf16_t sA [NBUF][BM * BK];
    __shared__ __align__(16) bf16_t sBU[NBUF][BN * BK];
    __shared__ __align__(16) bf16_t sBZ[NBUF][BN * BK];
    __shared__ float red[8];

    const int t    = threadIdx.x;
    const int lane = t & 63;
    const int wave = t >> 6;        // 0..7
    const int wm   = wave >> 2;     // 0..1 -> 64 rows
    const int wn   = wave & 3;      // 0..3 -> 32 cols
    const int m    = blockIdx.x >> 3;   // 0..31 (slice)
    const int n    = blockIdx.x & 7;    // 0..7
    const int m0   = m * BM;
    const int n0   = n * BN;
    const int lr   = lane & 15;
    const int lkb  = (lane >> 4) * 8;
    const int prow = (lane >> 4) * 4;

    const int srow = wave * 16 + (lane >> 2);
    const int scol = (lane & 3) * 8;
    const bf16_t* gBu = wg + (int64_t)(n0 + srow) * DIN + scol;
    const bf16_t* gBz = wc + (int64_t)(n0 + srow) * DIN + scol;

    float uSt[4][2][4];            // u tile (U role state)
    float zSt[4][2][4];            // z tile (Z role state)
    unsigned int eyp[4][2][2];     // e_y packed 2x bf16 per reg
    float esum = 0.0f;

    const bf16_t* Asrc = exA;
    bf16_t*       Adst = exB;

    for (int it = 0; it < NITER; ++it) {
        const bf16_t* gA = Asrc + (int64_t)(m0 + srow) * DIN + scol;
        f32x4 accU[4][2] = {};
        f32x4 accZ[4][2] = {};

        auto stage = [&](int tile, int buf) {
            const int64_t ko = (int64_t)tile * BK;
            GLDS(gA  + ko, &sA [buf][wave * 512]);
            GLDS(gBu + ko, &sBU[buf][wave * 512]);
            GLDS(gBz + ko, &sBZ[buf][wave * 512]);
        };
        auto compute = [&](int buf) {
            bf16x8 af[4], bu[2], bz[2];
#pragma unroll
            for (int mi = 0; mi < 4; ++mi)
                af[mi] = *reinterpret_cast<const bf16x8*>(
                    &sA[buf][(wm * 64 + mi * 16 + lr) * BK + lkb]);
#pragma unroll
            for (int ni = 0; ni < 2; ++ni) {
                bu[ni] = *reinterpret_cast<const bf16x8*>(
                    &sBU[buf][(wn * 32 + ni * 16 + lr) * BK + lkb]);
                bz[ni] = *reinterpret_cast<const bf16x8*>(
                    &sBZ[buf][(wn * 32 + ni * 16 + lr) * BK + lkb]);
            }
#pragma unroll
            for (int mi = 0; mi < 4; ++mi)
#pragma unroll
                for (int ni = 0; ni < 2; ++ni) {
                    accU[mi][ni] = __builtin_amdgcn_mfma_f32_16x16x32_bf16(
                        af[mi], bu[ni], accU[mi][ni], 0, 0, 0);
                    accZ[mi][ni] = __builtin_amdgcn_mfma_f32_16x16x32_bf16(
                        af[mi], bz[ni], accZ[mi][ni], 0, 0, 0);
                }
        };

        const int npairs = (DIN / BK) / 2;   // 16
        stage(0, 0); stage(1, 1); stage(2, 2); stage(3, 3);   // 12 loads
        for (int p = 0; p < npairs - 2; ++p) {
            const int t0 = 2 * p;
            WAITVM(6);                 // pair p landed; next pair flying
            BAR();
            SCHEDB();
            compute(t0 & 3);
            compute((t0 + 1) & 3);
            BAR();
            stage(t0 + 4, t0 & 3);     // back to 12 in flight; never 0
            stage(t0 + 5, (t0 + 1) & 3);
        }
        {
            const int t0 = 2 * npairs - 4;
            WAITVM(6); BAR(); SCHEDB();
            compute(t0 & 3); compute((t0 + 1) & 3);
        }
        {
            const int t0 = 2 * npairs - 2;
            WAITVM(0); BAR(); SCHEDB();
            compute(t0 & 3); compute((t0 + 1) & 3);
        }

        // epilogues: C mapping col=lane&15, row=(lane>>4)*4+j
#pragma unroll
        for (int mi = 0; mi < 4; ++mi) {
#pragma unroll
            for (int ni = 0; ni < 2; ++ni) {
                const int col = n0 + wn * 32 + ni * 16 + lr;
#pragma unroll
                for (int j = 0; j < 4; ++j) {
                    const int row = m0 + wm * 64 + mi * 16 + prow + j;
                    // ---- U role (skip on last iteration) ----
                    if (it != NITER - 1) {
                        const int64_t idx = (int64_t)row * DIN + col;
                        const float D = LR * accU[mi][ni][j];
                        const float base = (it == 0) ? bias_g[col]
                                                     : uSt[mi][ni][j];
                        const float un = base + D;
                        uSt[mi][ni][j] = un;
                        const float xp = 1.0f / (1.0f + __expf(-un));
                        const float e  = xin[idx] - xp;
                        Adst[idx] = (bf16_t)e;
                        esum += e * e;
                    }
                    // ---- Z role ----
                    if (col < DOUT) {
                        const float D = LR * accZ[mi][ni][j];
                        const float base = (it == 0) ? bias_o[col]
                                                     : zSt[mi][ni][j];
                        const float zn = base + D;
                        zSt[mi][ni][j] = zn;
                        const unsigned int w = eyp[mi][ni][j >> 1];
                        const float eyold = bf16_val(
                            (j & 1) ? (unsigned short)(w >> 16)
                                    : (unsigned short)(w & 0xFFFFu));
                        const float eyn =
                            (it == 0) ? -zn : (1.0f + LR) * eyold - D;
                        if (it == NITER - 1) {
                            yout[(int64_t)row * DOUT + col] =
                                (1.0f + LR) * eyn + zn;
                        } else {
                            const unsigned int b = bf16_bits(eyn);
                            eyp[mi][ni][j >> 1] =
                                (j & 1) ? ((w & 0x0000FFFFu) | (b << 16))
                                        : ((w & 0xFFFF0000u) | b);
                        }
                        esum += eyn * eyn;
                    }
                }
            }
        }

        // ---- slice barrier: 8 blocks sharing m-slice, monotonic counter ----
        if (it != NITER - 1) {
            __syncthreads();
            if (t == 0) {
                __threadfence();                       // publish e_x' stores
                atomicAdd(&barcnt[m], 1u);
                const unsigned int tgt = 8u * (unsigned int)(it + 1);
                while (atomicAdd(&barcnt[m], 0u) < tgt)
                    __builtin_amdgcn_s_sleep(8);
                __threadfence();                       // acquire peers' stores
            }
            __syncthreads();
        }
        bf16_t* tmp = Adst; Adst = (bf16_t*)Asrc; Asrc = tmp;
    }

    // energy reduction: esum accumulated over all iterations
#pragma unroll
    for (int off = 32; off; off >>= 1) esum += __shfl_down(esum, off, 64);
    if (lane == 0) red[wave] = esum;
    __syncthreads();
    if (t == 0) {
        float s = 0.0f;
#pragma unroll
        for (int w = 0; w < 8; ++w) s += red[w];
        atomicAdd(energy, s);
    }
}

// ---------------------------------------------------------------------------
// setup: Wg = W_rec^T W_rec (role 0), Wc = W_out W_rec (role 1); K = 2048.
// R6-proven GEMM core, plain C-store epilogue.  Runs once.
// ---------------------------------------------------------------------------
__global__ __launch_bounds__(512) void setup_gemm(
    const bf16_t* __restrict__ wrecT, const bf16_t* __restrict__ woutP,
    bf16_t* __restrict__ wg, bf16_t* __restrict__ wc)
{
    __shared__ __align__(16) bf16_t sA[NBUF][BM * BK];
    __shared__ __align__(16) bf16_t sB[NBUF][BN * BK];

    const int t    = threadIdx.x;
    const int lane = t & 63;
    const int wave = t >> 6;
    const int wm   = wave >> 2;
    const int wn   = wave & 3;
    const int m0   = blockIdx.x * BM;
    const int role = (int)blockIdx.y >= 8;
    const int n0   = ((int)blockIdx.y & 7) * BN;
    const int lr   = lane & 15;
    const int lkb  = (lane >> 4) * 8;
    const int prow = (lane >> 4) * 4;

    f32x4 acc[4][2] = {};

    const int srow = wave * 16 + (lane >> 2);
    const int scol = (lane & 3) * 8;
    const bf16_t* gA = (role ? woutP : wrecT) + (int64_t)(m0 + srow) * HID + scol;
    const bf16_t* gB = wrecT + (int64_t)(n0 + srow) * HID + scol;

    auto stage = [&](int tile, int buf) {
        const int64_t ko = (int64_t)tile * BK;
        GLDS(gA + ko, &sA[buf][wave * 512]);
        GLDS(gB + ko, &sB[buf][wave * 512]);
    };
    auto compute = [&](int buf) {
        bf16x8 af[4], bfr[2];
#pragma unroll
        for (int mi = 0; mi < 4; ++mi)
            af[mi] = *reinterpret_cast<const bf16x8*>(
                &sA[buf][(wm * 64 + mi * 16 + lr) * BK + lkb]);
#pragma unroll
        for (int ni = 0; ni < 2; ++ni)
            bfr[ni] = *reinterpret_cast<const bf16x8*>(
                &sB[buf][(wn * 32 + ni * 16 + lr) * BK + lkb]);
#pragma unroll
        for (int mi = 0; mi < 4; ++mi)
#pragma unroll
            for (int ni = 0; ni < 2; ++ni)
                acc[mi][ni] = __builtin_amdgcn_mfma_f32_16x16x32_bf16(
                    af[mi], bfr[ni], acc[mi][ni], 0, 0, 0);
    };

    const int npairs = (HID / BK) / 2;   // 32
    stage(0, 0); stage(1, 1); stage(2, 2); stage(3, 3);
    for (int p = 0; p < npairs - 2; ++p) {
        const int t0 = 2 * p;
        WAITVM(4); BAR(); SCHEDB();
        compute(t0 & 3); compute((t0 + 1) & 3);
        BAR();
        stage(t0 + 4, t0 & 3); stage(t0 + 5, (t0 + 1) & 3);
    }
    {
        const int t0 = 2 * npairs - 4;
        WAITVM(4); BAR(); SCHEDB();
        compute(t0 & 3); compute((t0 + 1) & 3);
    }
    {
        const int t0 = 2 * npairs - 2;
        WAITVM(0); BAR(); SCHEDB();
        compute(t0 & 3); compute((t0 + 1) & 3);
    }

    bf16_t* cout = role ? wc : wg;
#pragma unroll
    for (int mi = 0; mi < 4; ++mi)
#pragma unroll
        for (int ni = 0; ni < 2; ++ni) {
            const int col = n0 + wn * 32 + ni * 16 + lr;
#pragma unroll
            for (int j = 0; j < 4; ++j) {
                const int row = m0 + wm * 64 + mi * 16 + prow + j;
                cout[(int64_t)row * 1024 + col] = (bf16_t)acc[mi][ni][j];
            }
        }
}

// W_rec [HID][DIN] f32 -> bf16 transpose [DIN][HID]
__global__ void conv_wrec(const float* __restrict__ W, bf16_t* __restrict__ WbT)
{
    __shared__ float tile[32][33];
    const int tx = threadIdx.x & 31;
    const int ty = threadIdx.x >> 5;
    const int c0 = blockIdx.x * 32;
    const int r0 = blockIdx.y * 32;
#pragma unroll
    for (int rr = ty; rr < 32; rr += 8)
        tile[rr][tx] = W[(int64_t)(r0 + rr) * DIN + c0 + tx];
    __syncthreads();
#pragma unroll
    for (int rr = ty; rr < 32; rr += 8)
        WbT[(int64_t)(c0 + rr) * HID + r0 + tx] = (bf16_t)tile[tx][rr];
}

// W_out [DOUT][HID] f32 -> bf16 [1024][HID], rows >= DOUT zero-padded
__global__ void conv_wout(const float* __restrict__ W, bf16_t* __restrict__ Wb)
{
    const int i = blockIdx.x * 256 + threadIdx.x;
    const int r = i >> 11;
    const int c = i & 2047;
    Wb[i] = (r < DOUT) ? (bf16_t)W[(int64_t)r * HID + c] : (bf16_t)0.0f;
}

// iteration 0: e_x_0 = x - sigmoid(b_gen), + its energy term
__global__ void ex0_kernel(const float* __restrict__ x,
                           const float* __restrict__ bias_g,
                           bf16_t* __restrict__ ex, float* __restrict__ energy)
{
    __shared__ float red[4];
    const int t = threadIdx.x, lane = t & 63, wave = t >> 6;
    const int i = (blockIdx.x * 256 + t) * 4;
    const int c0 = i & (DIN - 1);
    const float4 v = *reinterpret_cast<const float4*>(&x[i]);
    float e[4];
    const float b0 = bias_g[c0], b1 = bias_g[c0 + 1],
                b2 = bias_g[c0 + 2], b3 = bias_g[c0 + 3];
    e[0] = v.x - 1.0f / (1.0f + __expf(-b0));
    e[1] = v.y - 1.0f / (1.0f + __expf(-b1));
    e[2] = v.z - 1.0f / (1.0f + __expf(-b2));
    e[3] = v.w - 1.0f / (1.0f + __expf(-b3));
    bf16x4 o = {(bf16_t)e[0], (bf16_t)e[1], (bf16_t)e[2], (bf16_t)e[3]};
    *reinterpret_cast<bf16x4*>(&ex[i]) = o;
    float esum = e[0]*e[0] + e[1]*e[1] + e[2]*e[2] + e[3]*e[3];
#pragma unroll
    for (int off = 32; off; off >>= 1) esum += __shfl_down(esum, off, 64);
    if (lane == 0) red[wave] = esum;
    __syncthreads();
    if (t == 0) atomicAdd(energy, red[0] + red[1] + red[2] + red[3]);
}

__global__ void finalize_kernel(const float* __restrict__ energy,
                                float* __restrict__ out)
{
    out[0] = energy[0] * (1.0f / ((float)BATCH * (float)NITER));
}

extern "C" void kernel_launch(void* const* d_in, const int* in_sizes, int n_in,
                              void* d_out, int out_size, void* d_ws, size_t ws_size,
                              hipStream_t stream)
{
    (void)in_sizes; (void)n_in; (void)out_size; (void)ws_size;
    const float* x        = (const float*)d_in[0];
    const float* W_rec    = (const float*)d_in[1];
    const float* W_out    = (const float*)d_in[2];
    const float* bias_out = (const float*)d_in[3];
    const float* bias_gen = (const float*)d_in[4];
    float* y = (float*)d_out; // [BATCH*DOUT] then [1] energy

    char* ws = (char*)d_ws;
    size_t off = 0;
    bf16_t* exA   = (bf16_t*)(ws + off);  off += (size_t)BATCH * DIN * 2;   // 8 MB
    bf16_t* exB   = (bf16_t*)(ws + off);  off += (size_t)BATCH * DIN * 2;   // 8 MB
    bf16_t* wrecT = (bf16_t*)(ws + off);  off += (size_t)DIN * HID * 2;     // 4 MB
    bf16_t* woutP = (bf16_t*)(ws + off);  off += (size_t)1024 * HID * 2;    // 4 MB
    bf16_t* wg    = (bf16_t*)(ws + off);  off += (size_t)1024 * 1024 * 2;   // 2 MB
    bf16_t* wc    = (bf16_t*)(ws + off);  off += (size_t)1024 * 1024 * 2;   // 2 MB
    float* energy = (float*)(ws + off);                                     // +256 B
    unsigned int* barcnt = (unsigned int*)(ws + off + 64);  // 32 counters

    // zero energy + barrier counters (fresh every call -> deterministic)
    hipMemsetAsync(energy, 0, 256, stream);

    conv_wrec<<<dim3(DIN / 32, HID / 32), 256, 0, stream>>>(W_rec, wrecT);
    conv_wout<<<(1024 * HID) / 256, 256, 0, stream>>>(W_out, woutP);
    setup_gemm<<<dim3(8, 16), 512, 0, stream>>>(wrecT, woutP, wg, wc);
    ex0_kernel<<<(BATCH * DIN) / 1024, 256, 0, stream>>>(x, bias_gen, exA, energy);

    pc_persist<<<dim3(256), dim3(512), 0, stream>>>(
        exA, exB, wg, wc, x, bias_gen, bias_out, y, energy, barcnt);

    finalize_kernel<<<1, 1, 0, stream>>>(energy, y + (size_t)BATCH * DOUT);
}